// Round 9
// baseline (319.735 us; speedup 1.0000x reference)
//
#include <hip/hip_runtime.h>
#include <hip/hip_bf16.h>

typedef __bf16 bf16x8 __attribute__((ext_vector_type(8)));
typedef __bf16 bf16x4 __attribute__((ext_vector_type(4)));
typedef float f32x4 __attribute__((ext_vector_type(4)));
typedef float f32x16 __attribute__((ext_vector_type(16)));

#define MFMA16(a,b,c) __builtin_amdgcn_mfma_f32_16x16x32_bf16((a),(b),(c),0,0,0)
#define MFMA32(a,b,c) __builtin_amdgcn_mfma_f32_32x32x16_bf16((a),(b),(c),0,0,0)

// async global->LDS, 16B per lane; lds dst = wave-uniform base + lane*16
__device__ __forceinline__ void gload_lds16(const void* g, void* l) {
    __builtin_amdgcn_global_load_lds((const __attribute__((address_space(1))) unsigned int*)g,
                                     (__attribute__((address_space(3))) unsigned int*)l, 16, 0, 0);
}

// ---------------- GroupNorm stats, stage 1 ----------------
__global__ __launch_bounds__(256) void gn_stats1(const float* __restrict__ x,
                                                 float* __restrict__ pstats) {
    int blk = blockIdx.x;            // 0..511
    int bg = blk >> 4, sl = blk & 15;
    int b = bg >> 3, g = bg & 7;
    const float* base = x + ((size_t)b * 4096 + sl * 256) * 256 + g * 32;
    float s = 0.f, s2 = 0.f;
    for (int i = threadIdx.x; i < 2048; i += 256) {
        int pos = i >> 3, f4 = i & 7;
        float4 v = *(const float4*)(base + (size_t)pos * 256 + f4 * 4);
        s  += v.x + v.y + v.z + v.w;
        s2 += v.x * v.x + v.y * v.y + v.z * v.z + v.w * v.w;
    }
    for (int off = 32; off; off >>= 1) {
        s  += __shfl_down(s, off);
        s2 += __shfl_down(s2, off);
    }
    __shared__ float red[8];
    int wave = threadIdx.x >> 6, lane = threadIdx.x & 63;
    if (lane == 0) { red[wave] = s; red[4 + wave] = s2; }
    __syncthreads();
    if (threadIdx.x == 0) {
        pstats[blk * 2]     = red[0] + red[1] + red[2] + red[3];
        pstats[blk * 2 + 1] = red[4] + red[5] + red[6] + red[7];
    }
}

// ---------------- GroupNorm stats, stage 2 ----------------
__global__ void gn_stats2(const float* __restrict__ pstats, float* __restrict__ stats) {
    int bg = threadIdx.x;
    if (bg < 32) {
        float S = 0.f, S2 = 0.f;
        for (int sl = 0; sl < 16; sl++) {
            S  += pstats[(bg * 16 + sl) * 2];
            S2 += pstats[(bg * 16 + sl) * 2 + 1];
        }
        const float invN = 1.f / 131072.f;
        float mean = S * invN;
        float var = S2 * invN - mean * mean;
        stats[bg * 2] = mean;
        stats[bg * 2 + 1] = rsqrtf(var + 1e-3f);
    }
}

// ---------------- GroupNorm normalize ----------------
__global__ __launch_bounds__(256) void gn_norm(const float* __restrict__ x,
                                               const float* __restrict__ gamma,
                                               const float* __restrict__ beta,
                                               const float* __restrict__ stats,
                                               float* __restrict__ xn_f32,
                                               __bf16* __restrict__ xn_bf) {
    size_t idx = (size_t)blockIdx.x * 256 + threadIdx.x;
    int c4 = (int)(idx & 63);
    int row = (int)(idx >> 6);
    int b = row >> 12;
    int g = c4 >> 3;
    float mean = stats[(b * 8 + g) * 2];
    float rstd = stats[(b * 8 + g) * 2 + 1];
    float4 xv = ((const float4*)x)[idx];
    float4 ga = ((const float4*)gamma)[c4];
    float4 be = ((const float4*)beta)[c4];
    float4 r;
    r.x = (xv.x - mean) * rstd * ga.x + be.x;
    r.y = (xv.y - mean) * rstd * ga.y + be.y;
    r.z = (xv.z - mean) * rstd * ga.z + be.z;
    r.w = (xv.w - mean) * rstd * ga.w + be.w;
    ((float4*)xn_f32)[idx] = r;
    bf16x4 o;
    o[0] = (__bf16)r.x; o[1] = (__bf16)r.y; o[2] = (__bf16)r.z; o[3] = (__bf16)r.w;
    *(bf16x4*)(xn_bf + idx * 4) = o;
}

// ---------------- Weight prep: fp32 [k][n] -> bf16 fragment-linear ----------------
__global__ __launch_bounds__(256) void prep_w(const float* __restrict__ Wq,
                                              const float* __restrict__ Wk,
                                              const float* __restrict__ Wv,
                                              const float* __restrict__ Wp,
                                              __bf16* __restrict__ wt) {
    int o = blockIdx.x * 256 + threadIdx.x;  // 0..262143
    int w = o >> 16;
    int rem = o & 65535;
    int nt   = rem >> 12;
    int kf   = (rem >> 9) & 7;
    int quad = (rem >> 7) & 3;
    int l16  = (rem >> 3) & 15;
    int j    = rem & 7;
    int n = nt * 16 + l16;
    int k = kf * 32 + quad * 8 + j;
    const float* W = (w == 0) ? Wq : (w == 1) ? Wk : (w == 2) ? Wv : Wp;
    wt[o] = (__bf16)W[k * 256 + n];
}

// ---------------- QKV GEMM: LDS A-tile; v stored transposed via LDS bounce ----------------
__global__ __launch_bounds__(128, 2) void qkv_gemm(const __bf16* __restrict__ xn,
                                                   const __bf16* __restrict__ wt,
                                                   const float* __restrict__ bq,
                                                   const float* __restrict__ bk,
                                                   const float* __restrict__ bv,
                                                   __bf16* __restrict__ qout,
                                                   __bf16* __restrict__ kout,
                                                   __bf16* __restrict__ vtout) {
    __shared__ __bf16 atile[64][264];
    int w = blockIdx.z;
    const __bf16* Wl = wt + (size_t)w * 65536;
    int tid = threadIdx.x;
    int wave = tid >> 6, lane = tid & 63;
    int quad = lane >> 4, l16 = lane & 15;
    int m0 = blockIdx.x * 64;
    int ntbase = blockIdx.y * 8 + wave * 4;

#pragma unroll
    for (int i = 0; i < 16; i++) {
        int c = tid + 128 * i;
        int row = c >> 5, col = (c & 31) * 8;
        *(bf16x8*)&atile[row][col] = *(const bf16x8*)(xn + (size_t)(m0 + row) * 256 + col);
    }
    bf16x8 bfr[4][8];
#pragma unroll
    for (int ct = 0; ct < 4; ct++)
#pragma unroll
        for (int kf = 0; kf < 8; kf++)
            bfr[ct][kf] = *(const bf16x8*)(Wl + ((((size_t)(ntbase + ct) * 8 + kf) * 4 + quad) * 16 + l16) * 8);
    __syncthreads();

    f32x4 acc[4][4];
#pragma unroll
    for (int mt = 0; mt < 4; mt++)
#pragma unroll
        for (int ct = 0; ct < 4; ct++)
#pragma unroll
            for (int r = 0; r < 4; r++) acc[mt][ct][r] = 0.f;
#pragma unroll
    for (int kf = 0; kf < 8; kf++) {
        bf16x8 af[4];
#pragma unroll
        for (int mt = 0; mt < 4; mt++)
            af[mt] = *(const bf16x8*)&atile[mt * 16 + l16][kf * 32 + quad * 8];
#pragma unroll
        for (int mt = 0; mt < 4; mt++)
#pragma unroll
            for (int ct = 0; ct < 4; ct++)
                acc[mt][ct] = MFMA16(af[mt], bfr[ct][kf], acc[mt][ct]);
    }

    if (w == 2) {
        // transposed store via LDS bounce (fix R8's 8B-scatter)
        __syncthreads();   // all waves done reading atile
        __bf16 (*vtl)[70] = (__bf16(*)[70])atile;    // 128 c x (64 n + pad)
#pragma unroll
        for (int mt = 0; mt < 4; mt++) {
#pragma unroll
            for (int ct = 0; ct < 4; ct++) {
                int cl = (wave * 4 + ct) * 16 + l16;   // 0..127 block-local channel
                float bias_v = bv[blockIdx.y * 128 + cl];
                bf16x4 pv;
#pragma unroll
                for (int r = 0; r < 4; r++) pv[r] = (__bf16)(acc[mt][ct][r] + bias_v);
                *(bf16x4*)&vtl[cl][mt * 16 + quad * 4] = pv;
            }
        }
        __syncthreads();
        int bb = m0 >> 12, n0g = m0 & 4095;
#pragma unroll
        for (int j = 0; j < 8; j++) {
            int chunk = tid + 128 * j;          // 0..1023
            int cl = chunk >> 3, n8 = chunk & 7;
            *(bf16x8*)(vtout + ((size_t)(bb * 256 + blockIdx.y * 128 + cl)) * 4096 + n0g + n8 * 8)
                = *(const bf16x8*)&vtl[cl][n8 * 8];
        }
    } else {
        const float* bias = (w == 0) ? bq : bk;
        // q pre-scaled by (1/16)*log2(e) so flash softmax runs in exp2 domain
        const float qscale = 0.09016844f;
#pragma unroll
        for (int mt = 0; mt < 4; mt++) {
#pragma unroll
            for (int ct = 0; ct < 4; ct++) {
                int c = (ntbase + ct) * 16 + l16;
                float bias_v = bias[c];
#pragma unroll
                for (int r = 0; r < 4; r++) {
                    int m = m0 + mt * 16 + quad * 4 + r;
                    float val = acc[mt][ct][r] + bias_v;
                    if (w == 0) qout[(size_t)m * 256 + c] = (__bf16)(val * qscale);
                    else        kout[(size_t)m * 256 + c] = (__bf16)val;
                }
            }
        }
    }
}

// ---------------- Flash attention v7: async dbuf, permuted V (b128 PV), exp2 softmax ----
// grid (32 qtiles, 4 ksplit, 4 batch) = 512 blocks, 256 thr (4 waves x 32 q-rows)
__global__ __launch_bounds__(256, 2) void flash_attn(const __bf16* __restrict__ q,
                                                     const __bf16* __restrict__ k,
                                                     const __bf16* __restrict__ vt,
                                                     __bf16* __restrict__ po,
                                                     float* __restrict__ ml) {
    __shared__ __align__(16) char smem[69632];
    // K dbuf at smem+0 / +16384 (XOR-swizzled 16B chunks); V dbuf padded+sigma-permuted
    __bf16 (*vtile0)[36] = (__bf16(*)[36])(smem + 32768);   // 18432 B
    __bf16 (*vtile1)[36] = (__bf16(*)[36])(smem + 51200);   // 18432 B
    __bf16 (*otr)[32][264] = (__bf16(*)[32][264])smem;      // epilogue overlay

    const int tid = threadIdx.x;
    const int wave = tid >> 6, lane = tid & 63;
    const int l32 = lane & 31, h = lane >> 5;
    const int qt = blockIdx.x, ks = blockIdx.y, b = blockIdx.z;
    const int row0 = qt * 128 + wave * 32;
    const size_t rowg0 = (size_t)b * 4096 + row0;

    const char*   kb = (const char*)(k + ((size_t)b * 4096 + ks * 1024) * 256);
    const __bf16* vb = vt + (size_t)b * 256 * 4096 + ks * 1024;

    int koff[4];
#pragma unroll
    for (int i = 0; i < 4; i++) {
        int P = wave * 256 + i * 64 + lane;
        int r = P >> 5, cp = P & 31;
        koff[i] = r * 512 + (cp ^ r) * 16;
    }
    const int kldsoff = wave * 4096;

    bf16x8 qf[16];
    const __bf16* qbase = q + (rowg0 + l32) * 256 + h * 8;
#pragma unroll
    for (int s = 0; s < 16; s++) qf[s] = *(const bf16x8*)(qbase + s * 16);

    f32x16 acc[8];
#pragma unroll
    for (int ct = 0; ct < 8; ct++)
#pragma unroll
        for (int r = 0; r < 16; r++) acc[ct][r] = 0.f;
    float mi = -1e30f, li = 0.f;

    // V staging: thread row vr_=tid>>2 (0..255 ch... here rows of vt are channels? no:
    // vb rows are channels 0..255; idx=tid+256i covers 256 ch x 4 chunks of 8 keys)
    const int vr_ = tid >> 2, vc4 = tid & 3;
    // sigma-permuted commit base for this thread's 8-key chunk
    const int vbase = 16 * (vc4 >> 1) + 4 * (vc4 & 1);

    // ---- prologue: stage tile 0 ----
#pragma unroll
    for (int i = 0; i < 4; i++)
        gload_lds16(kb + koff[i], smem + kldsoff + i * 1024);
    {
        bf16x8 vc[4];
#pragma unroll
        for (int i = 0; i < 4; i++)
            vc[i] = *(const bf16x8*)(vb + (size_t)(vr_ + 64 * i) * 4096 + vc4 * 8);
#pragma unroll
        for (int i = 0; i < 4; i++) {
            bf16x4 lo = __builtin_shufflevector(vc[i], vc[i], 0, 1, 2, 3);
            bf16x4 hi = __builtin_shufflevector(vc[i], vc[i], 4, 5, 6, 7);
            *(bf16x4*)&vtile0[vr_ + 64 * i][vbase]     = lo;
            *(bf16x4*)&vtile0[vr_ + 64 * i][vbase + 8] = hi;
        }
    }
    __syncthreads();

    for (int it = 0; it < 32; ++it) {
        const int cur = it & 1;
        char* kcur = smem + (cur ? 16384 : 0);
        char* knxt = smem + (cur ? 0 : 16384);
        __bf16 (*vcur)[36] = cur ? vtile1 : vtile0;
        __bf16 (*vnxt)[36] = cur ? vtile0 : vtile1;

        // ---- prefetch tile it+1: K async to LDS; V into registers ----
        bf16x8 vc[4];
        if (it + 1 < 32) {
            const char* kg = kb + (size_t)(it + 1) * 16384;
#pragma unroll
            for (int i = 0; i < 4; i++)
                gload_lds16(kg + koff[i], knxt + kldsoff + i * 1024);
            const int kn = (it + 1) * 32;
#pragma unroll
            for (int i = 0; i < 4; i++)
                vc[i] = *(const bf16x8*)(vb + (size_t)(vr_ + 64 * i) * 4096 + kn + vc4 * 8);
        }

        // ---- S^T = K . Q^T (swizzled K reads) ----
        f32x16 s;
#pragma unroll
        for (int r = 0; r < 16; r++) s[r] = 0.f;
#pragma unroll
        for (int kf = 0; kf < 16; kf++) {
            int cl = kf * 2 + h;
            bf16x8 ka = *(const bf16x8*)(kcur + l32 * 512 + ((cl ^ l32) << 4));
            s = MFMA32(ka, qf[kf], s);
        }

        // ---- commit V prefetch (sigma-permuted; V loads had the whole QK to land) ----
        if (it + 1 < 32) {
#pragma unroll
            for (int i = 0; i < 4; i++) {
                bf16x4 lo = __builtin_shufflevector(vc[i], vc[i], 0, 1, 2, 3);
                bf16x4 hi = __builtin_shufflevector(vc[i], vc[i], 4, 5, 6, 7);
                *(bf16x4*)&vnxt[vr_ + 64 * i][vbase]     = lo;
                *(bf16x4*)&vnxt[vr_ + 64 * i][vbase + 8] = hi;
            }
        }

        // ---- online softmax in exp2 domain (q pre-scaled by log2e/16) ----
        float mx = s[0];
#pragma unroll
        for (int r = 1; r < 16; r++) mx = fmaxf(mx, s[r]);
        mx = fmaxf(mx, __shfl_xor(mx, 32));
        float mnew = fmaxf(mi, mx);
        float alpha = exp2f(mi - mnew);
        float rs = 0.f;
#pragma unroll
        for (int r = 0; r < 16; r++) { float p = exp2f(s[r] - mnew); s[r] = p; rs += p; }
        rs += __shfl_xor(rs, 32);
        li = li * alpha + rs;
        bool need = (mnew > mi);
        mi = mnew;
        bf16x8 pf0, pf1;
#pragma unroll
        for (int j = 0; j < 8; j++) { pf0[j] = (__bf16)s[j]; pf1[j] = (__bf16)s[8 + j]; }
        if (__ballot(need)) {
#pragma unroll
            for (int ct = 0; ct < 8; ct++)
#pragma unroll
                for (int r = 0; r < 16; r++) acc[ct][r] *= alpha;
        }

        // ---- O^T += V^T . P : sigma-permuted V gives contiguous b128 A-frags ----
#pragma unroll
        for (int ct = 0; ct < 8; ct++) {
            const __bf16* vr = &vcur[ct * 32 + l32][0];
            bf16x8 va0 = *(const bf16x8*)(vr + 8 * h);
            acc[ct] = MFMA32(va0, pf0, acc[ct]);
            bf16x8 va1 = *(const bf16x8*)(vr + 16 + 8 * h);
            acc[ct] = MFMA32(va1, pf1, acc[ct]);
        }
        __syncthreads();   // single barrier: drains K async prefetch + orders buffers
    }

    // epilogue: transpose O^T -> row-major via wave-private LDS region
#pragma unroll
    for (int ct = 0; ct < 8; ct++) {
#pragma unroll
        for (int pk = 0; pk < 4; pk++) {
            bf16x4 op;
            op[0] = (__bf16)acc[ct][pk * 4];     op[1] = (__bf16)acc[ct][pk * 4 + 1];
            op[2] = (__bf16)acc[ct][pk * 4 + 2]; op[3] = (__bf16)acc[ct][pk * 4 + 3];
            *(bf16x4*)&otr[wave][l32][ct * 32 + pk * 8 + h * 4] = op;
        }
    }
    if (lane < 32) {
        float2 v; v.x = mi; v.y = li;    // mi in log2 domain
        *(float2*)&ml[((size_t)ks * 16384 + rowg0 + l32) * 2] = v;
    }
    __syncthreads();
    __bf16* pobase = po + ((size_t)ks * 16384 + rowg0) * 256;
    const int rr = lane >> 1, half = lane & 1;
#pragma unroll
    for (int j = 0; j < 16; j++) {
        bf16x8 val = *(const bf16x8*)&otr[wave][rr][half * 128 + j * 8];
        *(bf16x8*)(pobase + (size_t)rr * 256 + half * 128 + j * 8) = val;
    }
}

// ---------------- Projection GEMM + fused 4-way merge + bias + residual ----------------
__global__ __launch_bounds__(128, 2) void proj_gemm(const __bf16* __restrict__ po,
                                                    const float* __restrict__ ml,
                                                    const __bf16* __restrict__ wpl,
                                                    const float* __restrict__ bp,
                                                    float* __restrict__ out) {
    __shared__ __bf16 atile[64][264];
    int tid = threadIdx.x;
    int wave = tid >> 6, lane = tid & 63;
    int quad = lane >> 4, l16 = lane & 15;
    int m0 = blockIdx.x * 64;
    int ntbase = blockIdx.y * 8 + wave * 4;

    // stage A-tile = merged attention output (4 key-split partials, exp2 domain)
#pragma unroll
    for (int i = 0; i < 16; i++) {
        int c = tid + 128 * i;
        int row = c >> 5, col8 = c & 31;
        int m = m0 + row;
        float mm[4], ll[4];
#pragma unroll
        for (int s = 0; s < 4; s++) {
            float2 v = *(const float2*)&ml[((size_t)s * 16384 + m) * 2];
            mm[s] = v.x; ll[s] = v.y;
        }
        float M = fmaxf(fmaxf(mm[0], mm[1]), fmaxf(mm[2], mm[3]));
        float den = 0.f, w[4];
#pragma unroll
        for (int s = 0; s < 4; s++) { w[s] = exp2f(mm[s] - M); den += ll[s] * w[s]; }
        float accv[8];
#pragma unroll
        for (int e = 0; e < 8; e++) accv[e] = 0.f;
#pragma unroll
        for (int s = 0; s < 4; s++) {
            bf16x8 pv = *(const bf16x8*)(po + ((size_t)s * 16384 + m) * 256 + col8 * 8);
#pragma unroll
            for (int e = 0; e < 8; e++) accv[e] += w[s] * (float)pv[e];
        }
        float rinv = 1.f / den;
        bf16x8 o;
#pragma unroll
        for (int e = 0; e < 8; e++) o[e] = (__bf16)(accv[e] * rinv);
        *(bf16x8*)&atile[row][col8 * 8] = o;
    }
    bf16x8 bfr[4][8];
#pragma unroll
    for (int ct = 0; ct < 4; ct++)
#pragma unroll
        for (int kf = 0; kf < 8; kf++)
            bfr[ct][kf] = *(const bf16x8*)(wpl + ((((size_t)(ntbase + ct) * 8 + kf) * 4 + quad) * 16 + l16) * 8);
    __syncthreads();

    f32x4 acc[4][4];
#pragma unroll
    for (int mt = 0; mt < 4; mt++)
#pragma unroll
        for (int ct = 0; ct < 4; ct++)
#pragma unroll
            for (int r = 0; r < 4; r++) acc[mt][ct][r] = 0.f;
#pragma unroll
    for (int kf = 0; kf < 8; kf++) {
        bf16x8 af[4];
#pragma unroll
        for (int mt = 0; mt < 4; mt++)
            af[mt] = *(const bf16x8*)&atile[mt * 16 + l16][kf * 32 + quad * 8];
#pragma unroll
        for (int mt = 0; mt < 4; mt++)
#pragma unroll
            for (int ct = 0; ct < 4; ct++)
                acc[mt][ct] = MFMA16(af[mt], bfr[ct][kf], acc[mt][ct]);
    }
#pragma unroll
    for (int mt = 0; mt < 4; mt++) {
#pragma unroll
        for (int ct = 0; ct < 4; ct++) {
            int c = (ntbase + ct) * 16 + l16;
            float bias_v = bp[c];
#pragma unroll
            for (int r = 0; r < 4; r++) {
                int m = m0 + mt * 16 + quad * 4 + r;
                size_t idx = (size_t)m * 256 + c;
                out[idx] = out[idx] + acc[mt][ct][r] + bias_v;
            }
        }
    }
}

extern "C" void kernel_launch(void* const* d_in, const int* in_sizes, int n_in,
                              void* d_out, int out_size, void* d_ws, size_t ws_size,
                              hipStream_t stream) {
    const float* x     = (const float*)d_in[0];
    const float* gamma = (const float*)d_in[1];
    const float* beta  = (const float*)d_in[2];
    const float* Wq    = (const float*)d_in[3];
    const float* bq    = (const float*)d_in[4];
    const float* Wk    = (const float*)d_in[5];
    const float* bk    = (const float*)d_in[6];
    const float* Wv    = (const float*)d_in[7];
    const float* bv    = (const float*)d_in[8];
    const float* Wp    = (const float*)d_in[9];
    const float* bp    = (const float*)d_in[10];
    float* out = (float*)d_out;

    char* ws = (char*)d_ws;
    __bf16* xn_bf   = (__bf16*)(ws);                    //  8,388,608 B
    __bf16* wt      = (__bf16*)(ws + 8388608);          //    524,288 B (fragment-linear)
    __bf16* qbuf    = (__bf16*)(ws + 8912896);          //  8,388,608 B
    __bf16* kbuf    = (__bf16*)(ws + 17301504);         //  8,388,608 B
    __bf16* vtbuf   = (__bf16*)(ws + 25690112);         //  8,388,608 B
    __bf16* po      = (__bf16*)(ws + 34078720);         // 33,554,432 B
    float*  ml      = (float*)(ws + 67633152);          //    524,288 B
    float*  pstats  = (float*)(ws + 68157440);          //      4,096 B
    float*  gstats  = (float*)(ws + 68161536);          //        256 B

    gn_stats1<<<512, 256, 0, stream>>>(x, pstats);
    gn_stats2<<<1, 64, 0, stream>>>(pstats, gstats);
    gn_norm<<<4096, 256, 0, stream>>>(x, gamma, beta, gstats, out, xn_bf);
    prep_w<<<1024, 256, 0, stream>>>(Wq, Wk, Wv, Wp, wt);
    qkv_gemm<<<dim3(256, 2, 3), 128, 0, stream>>>(xn_bf, wt, bq, bk, bv, qbuf, kbuf, vtbuf);
    flash_attn<<<dim3(32, 4, 4), 256, 0, stream>>>(qbuf, kbuf, vtbuf, po, ml);
    proj_gemm<<<dim3(256, 2), 128, 0, stream>>>(po, ml, wt + 3 * 65536, bp, out);
}

// Round 10
// 253.721 us; speedup vs baseline: 1.2602x; 1.2602x over previous
//
#include <hip/hip_runtime.h>
#include <hip/hip_bf16.h>

typedef __bf16 bf16x8 __attribute__((ext_vector_type(8)));
typedef __bf16 bf16x4 __attribute__((ext_vector_type(4)));
typedef float f32x4 __attribute__((ext_vector_type(4)));
typedef float f32x16 __attribute__((ext_vector_type(16)));

#define MFMA16(a,b,c) __builtin_amdgcn_mfma_f32_16x16x32_bf16((a),(b),(c),0,0,0)
#define MFMA32(a,b,c) __builtin_amdgcn_mfma_f32_32x32x16_bf16((a),(b),(c),0,0,0)

// async global->LDS, 16B per lane; lds dst = wave-uniform base + lane*16
__device__ __forceinline__ void gload_lds16(const void* g, void* l) {
    __builtin_amdgcn_global_load_lds((const __attribute__((address_space(1))) unsigned int*)g,
                                     (__attribute__((address_space(3))) unsigned int*)l, 16, 0, 0);
}

// ---------------- GroupNorm stats, stage 1 ----------------
__global__ __launch_bounds__(256) void gn_stats1(const float* __restrict__ x,
                                                 float* __restrict__ pstats) {
    int blk = blockIdx.x;            // 0..511
    int bg = blk >> 4, sl = blk & 15;
    int b = bg >> 3, g = bg & 7;
    const float* base = x + ((size_t)b * 4096 + sl * 256) * 256 + g * 32;
    float s = 0.f, s2 = 0.f;
    for (int i = threadIdx.x; i < 2048; i += 256) {
        int pos = i >> 3, f4 = i & 7;
        float4 v = *(const float4*)(base + (size_t)pos * 256 + f4 * 4);
        s  += v.x + v.y + v.z + v.w;
        s2 += v.x * v.x + v.y * v.y + v.z * v.z + v.w * v.w;
    }
    for (int off = 32; off; off >>= 1) {
        s  += __shfl_down(s, off);
        s2 += __shfl_down(s2, off);
    }
    __shared__ float red[8];
    int wave = threadIdx.x >> 6, lane = threadIdx.x & 63;
    if (lane == 0) { red[wave] = s; red[4 + wave] = s2; }
    __syncthreads();
    if (threadIdx.x == 0) {
        pstats[blk * 2]     = red[0] + red[1] + red[2] + red[3];
        pstats[blk * 2 + 1] = red[4] + red[5] + red[6] + red[7];
    }
}

// ---------------- GroupNorm stats, stage 2 ----------------
__global__ void gn_stats2(const float* __restrict__ pstats, float* __restrict__ stats) {
    int bg = threadIdx.x;
    if (bg < 32) {
        float S = 0.f, S2 = 0.f;
        for (int sl = 0; sl < 16; sl++) {
            S  += pstats[(bg * 16 + sl) * 2];
            S2 += pstats[(bg * 16 + sl) * 2 + 1];
        }
        const float invN = 1.f / 131072.f;
        float mean = S * invN;
        float var = S2 * invN - mean * mean;
        stats[bg * 2] = mean;
        stats[bg * 2 + 1] = rsqrtf(var + 1e-3f);
    }
}

// ---------------- GroupNorm normalize ----------------
__global__ __launch_bounds__(256) void gn_norm(const float* __restrict__ x,
                                               const float* __restrict__ gamma,
                                               const float* __restrict__ beta,
                                               const float* __restrict__ stats,
                                               float* __restrict__ xn_f32,
                                               __bf16* __restrict__ xn_bf) {
    size_t idx = (size_t)blockIdx.x * 256 + threadIdx.x;
    int c4 = (int)(idx & 63);
    int row = (int)(idx >> 6);
    int b = row >> 12;
    int g = c4 >> 3;
    float mean = stats[(b * 8 + g) * 2];
    float rstd = stats[(b * 8 + g) * 2 + 1];
    float4 xv = ((const float4*)x)[idx];
    float4 ga = ((const float4*)gamma)[c4];
    float4 be = ((const float4*)beta)[c4];
    float4 r;
    r.x = (xv.x - mean) * rstd * ga.x + be.x;
    r.y = (xv.y - mean) * rstd * ga.y + be.y;
    r.z = (xv.z - mean) * rstd * ga.z + be.z;
    r.w = (xv.w - mean) * rstd * ga.w + be.w;
    ((float4*)xn_f32)[idx] = r;
    bf16x4 o;
    o[0] = (__bf16)r.x; o[1] = (__bf16)r.y; o[2] = (__bf16)r.z; o[3] = (__bf16)r.w;
    *(bf16x4*)(xn_bf + idx * 4) = o;
}

// ---------------- Weight prep: fp32 [k][n] -> bf16 fragment-linear ----------------
__global__ __launch_bounds__(256) void prep_w(const float* __restrict__ Wq,
                                              const float* __restrict__ Wk,
                                              const float* __restrict__ Wv,
                                              const float* __restrict__ Wp,
                                              __bf16* __restrict__ wt) {
    int o = blockIdx.x * 256 + threadIdx.x;  // 0..262143
    int w = o >> 16;
    int rem = o & 65535;
    int nt   = rem >> 12;
    int kf   = (rem >> 9) & 7;
    int quad = (rem >> 7) & 3;
    int l16  = (rem >> 3) & 15;
    int j    = rem & 7;
    int n = nt * 16 + l16;
    int k = kf * 32 + quad * 8 + j;
    const float* W = (w == 0) ? Wq : (w == 1) ? Wk : (w == 2) ? Wv : Wp;
    wt[o] = (__bf16)W[k * 256 + n];
}

// ---------------- QKV GEMM: LDS A-tile; v stored transposed via LDS bounce ----------------
__global__ __launch_bounds__(128, 2) void qkv_gemm(const __bf16* __restrict__ xn,
                                                   const __bf16* __restrict__ wt,
                                                   const float* __restrict__ bq,
                                                   const float* __restrict__ bk,
                                                   const float* __restrict__ bv,
                                                   __bf16* __restrict__ qout,
                                                   __bf16* __restrict__ kout,
                                                   __bf16* __restrict__ vtout) {
    __shared__ __bf16 atile[64][264];
    int w = blockIdx.z;
    const __bf16* Wl = wt + (size_t)w * 65536;
    int tid = threadIdx.x;
    int wave = tid >> 6, lane = tid & 63;
    int quad = lane >> 4, l16 = lane & 15;
    int m0 = blockIdx.x * 64;
    int ntbase = blockIdx.y * 8 + wave * 4;

#pragma unroll
    for (int i = 0; i < 16; i++) {
        int c = tid + 128 * i;
        int row = c >> 5, col = (c & 31) * 8;
        *(bf16x8*)&atile[row][col] = *(const bf16x8*)(xn + (size_t)(m0 + row) * 256 + col);
    }
    bf16x8 bfr[4][8];
#pragma unroll
    for (int ct = 0; ct < 4; ct++)
#pragma unroll
        for (int kf = 0; kf < 8; kf++)
            bfr[ct][kf] = *(const bf16x8*)(Wl + ((((size_t)(ntbase + ct) * 8 + kf) * 4 + quad) * 16 + l16) * 8);
    __syncthreads();

    f32x4 acc[4][4];
#pragma unroll
    for (int mt = 0; mt < 4; mt++)
#pragma unroll
        for (int ct = 0; ct < 4; ct++)
#pragma unroll
            for (int r = 0; r < 4; r++) acc[mt][ct][r] = 0.f;
#pragma unroll
    for (int kf = 0; kf < 8; kf++) {
        bf16x8 af[4];
#pragma unroll
        for (int mt = 0; mt < 4; mt++)
            af[mt] = *(const bf16x8*)&atile[mt * 16 + l16][kf * 32 + quad * 8];
#pragma unroll
        for (int mt = 0; mt < 4; mt++)
#pragma unroll
            for (int ct = 0; ct < 4; ct++)
                acc[mt][ct] = MFMA16(af[mt], bfr[ct][kf], acc[mt][ct]);
    }

    if (w == 2) {
        // transposed store via LDS bounce (coalesced 16B stores)
        __syncthreads();   // all waves done reading atile
        __bf16 (*vtl)[70] = (__bf16(*)[70])atile;    // 128 c x (64 n + pad)
#pragma unroll
        for (int mt = 0; mt < 4; mt++) {
#pragma unroll
            for (int ct = 0; ct < 4; ct++) {
                int cl = (wave * 4 + ct) * 16 + l16;   // 0..127 block-local channel
                float bias_v = bv[blockIdx.y * 128 + cl];
                bf16x4 pv;
#pragma unroll
                for (int r = 0; r < 4; r++) pv[r] = (__bf16)(acc[mt][ct][r] + bias_v);
                *(bf16x4*)&vtl[cl][mt * 16 + quad * 4] = pv;
            }
        }
        __syncthreads();
        int bb = m0 >> 12, n0g = m0 & 4095;
#pragma unroll
        for (int j = 0; j < 8; j++) {
            int chunk = tid + 128 * j;          // 0..1023
            int cl = chunk >> 3, n8 = chunk & 7;
            *(bf16x8*)(vtout + ((size_t)(bb * 256 + blockIdx.y * 128 + cl)) * 4096 + n0g + n8 * 8)
                = *(const bf16x8*)&vtl[cl][n8 * 8];
        }
    } else {
        const float* bias = (w == 0) ? bq : bk;
        // q pre-scaled by (1/16)*log2(e) so flash softmax runs in exp2 domain
        const float qscale = 0.09016844f;
#pragma unroll
        for (int mt = 0; mt < 4; mt++) {
#pragma unroll
            for (int ct = 0; ct < 4; ct++) {
                int c = (ntbase + ct) * 16 + l16;
                float bias_v = bias[c];
#pragma unroll
                for (int r = 0; r < 4; r++) {
                    int m = m0 + mt * 16 + quad * 4 + r;
                    float val = acc[mt][ct][r] + bias_v;
                    if (w == 0) qout[(size_t)m * 256 + c] = (__bf16)(val * qscale);
                    else        kout[(size_t)m * 256 + c] = (__bf16)val;
                }
            }
        }
    }
}

// ---------------- Flash attention v8: R8 structure exactly, exp2 softmax only change ----
// grid (32 qtiles, 4 ksplit, 4 batch) = 512 blocks, 256 thr (4 waves x 32 q-rows)
__global__ __launch_bounds__(256, 2) void flash_attn(const __bf16* __restrict__ q,
                                                     const __bf16* __restrict__ k,
                                                     const __bf16* __restrict__ vt,
                                                     __bf16* __restrict__ po,
                                                     float* __restrict__ ml) {
    __shared__ __align__(16) char smem[69632];
    // K dbuf at smem+0 / +16384, unpadded, XOR-swizzled 16B chunks (cp holds cl = cp ^ row)
    __bf16 (*vtile0)[36] = (__bf16(*)[36])(smem + 32768);   // 18432 B
    __bf16 (*vtile1)[36] = (__bf16(*)[36])(smem + 51200);   // 18432 B
    __bf16 (*otr)[32][264] = (__bf16(*)[32][264])smem;      // epilogue overlay

    const int tid = threadIdx.x;
    const int wave = tid >> 6, lane = tid & 63;
    const int l32 = lane & 31, h = lane >> 5;
    const int qt = blockIdx.x, ks = blockIdx.y, b = blockIdx.z;
    const int row0 = qt * 128 + wave * 32;
    const size_t rowg0 = (size_t)b * 4096 + row0;

    const char*   kb = (const char*)(k + ((size_t)b * 4096 + ks * 1024) * 256);
    const __bf16* vb = vt + (size_t)b * 256 * 4096 + ks * 1024;

    int koff[4];
#pragma unroll
    for (int i = 0; i < 4; i++) {
        int P = wave * 256 + i * 64 + lane;
        int r = P >> 5, cp = P & 31;
        koff[i] = r * 512 + (cp ^ r) * 16;
    }
    const int kldsoff = wave * 4096;

    bf16x8 qf[16];
    const __bf16* qbase = q + (rowg0 + l32) * 256 + h * 8;
#pragma unroll
    for (int s = 0; s < 16; s++) qf[s] = *(const bf16x8*)(qbase + s * 16);

    f32x16 acc[8];
#pragma unroll
    for (int ct = 0; ct < 8; ct++)
#pragma unroll
        for (int r = 0; r < 16; r++) acc[ct][r] = 0.f;
    float mi = -1e30f, li = 0.f;

    // V staging: vb rows are channels 0..255; idx=tid+256i covers 256 ch x 4 chunks of 8 keys
    const int vr_ = tid >> 2, vc4 = tid & 3;

    // ---- prologue: stage tile 0 ----
#pragma unroll
    for (int i = 0; i < 4; i++)
        gload_lds16(kb + koff[i], smem + kldsoff + i * 1024);
    {
        bf16x8 vc[4];
#pragma unroll
        for (int i = 0; i < 4; i++)
            vc[i] = *(const bf16x8*)(vb + (size_t)(vr_ + 64 * i) * 4096 + vc4 * 8);
#pragma unroll
        for (int i = 0; i < 4; i++)
            *(bf16x8*)&vtile0[vr_ + 64 * i][vc4 * 8] = vc[i];
    }
    __syncthreads();

    for (int it = 0; it < 32; ++it) {
        const int cur = it & 1;
        char* kcur = smem + (cur ? 16384 : 0);
        char* knxt = smem + (cur ? 0 : 16384);
        __bf16 (*vcur)[36] = cur ? vtile1 : vtile0;
        __bf16 (*vnxt)[36] = cur ? vtile0 : vtile1;

        // ---- prefetch tile it+1: K async to LDS; V into registers ----
        bf16x8 vc[4];
        if (it + 1 < 32) {
            const char* kg = kb + (size_t)(it + 1) * 16384;
#pragma unroll
            for (int i = 0; i < 4; i++)
                gload_lds16(kg + koff[i], knxt + kldsoff + i * 1024);
            const int kn = (it + 1) * 32;
#pragma unroll
            for (int i = 0; i < 4; i++)
                vc[i] = *(const bf16x8*)(vb + (size_t)(vr_ + 64 * i) * 4096 + kn + vc4 * 8);
        }

        // ---- S^T = K . Q^T (swizzled K reads) ----
        f32x16 s;
#pragma unroll
        for (int r = 0; r < 16; r++) s[r] = 0.f;
#pragma unroll
        for (int kf = 0; kf < 16; kf++) {
            int cl = kf * 2 + h;
            bf16x8 ka = *(const bf16x8*)(kcur + l32 * 512 + ((cl ^ l32) << 4));
            s = MFMA32(ka, qf[kf], s);
        }
        // ---- online softmax in exp2 domain (q pre-scaled by log2e/16) ----
        float mx = s[0];
#pragma unroll
        for (int r = 1; r < 16; r++) mx = fmaxf(mx, s[r]);
        mx = fmaxf(mx, __shfl_xor(mx, 32));
        float mnew = fmaxf(mi, mx);
        float alpha = exp2f(mi - mnew);
        float rs = 0.f;
#pragma unroll
        for (int r = 0; r < 16; r++) { float p = exp2f(s[r] - mnew); s[r] = p; rs += p; }
        rs += __shfl_xor(rs, 32);
        li = li * alpha + rs;
        bool need = (mnew > mi);
        mi = mnew;
        // P B-frags directly from registers (sigma-permuted k-slots, verified R3/R6)
        bf16x8 pf0, pf1;
#pragma unroll
        for (int j = 0; j < 8; j++) { pf0[j] = (__bf16)s[j]; pf1[j] = (__bf16)s[8 + j]; }
        if (__ballot(need)) {
#pragma unroll
            for (int ct = 0; ct < 8; ct++)
#pragma unroll
                for (int r = 0; r < 16; r++) acc[ct][r] *= alpha;
        }
        // ---- commit V prefetch to LDS (R8 placement: after softmax) ----
        if (it + 1 < 32) {
#pragma unroll
            for (int i = 0; i < 4; i++)
                *(bf16x8*)&vnxt[vr_ + 64 * i][vc4 * 8] = vc[i];
        }
        // ---- O^T += V^T . P (sigma-permuted V A-frags from LDS, b64 pairs = 2-way free) ----
#pragma unroll
        for (int ct = 0; ct < 8; ct++) {
            const __bf16* vr = &vcur[ct * 32 + l32][0];
            bf16x4 a00 = *(const bf16x4*)(vr + 4 * h);
            bf16x4 a01 = *(const bf16x4*)(vr + 8 + 4 * h);
            bf16x8 va0 = __builtin_shufflevector(a00, a01, 0, 1, 2, 3, 4, 5, 6, 7);
            acc[ct] = MFMA32(va0, pf0, acc[ct]);
            bf16x4 a10 = *(const bf16x4*)(vr + 16 + 4 * h);
            bf16x4 a11 = *(const bf16x4*)(vr + 24 + 4 * h);
            bf16x8 va1 = __builtin_shufflevector(a10, a11, 0, 1, 2, 3, 4, 5, 6, 7);
            acc[ct] = MFMA32(va1, pf1, acc[ct]);
        }
        __syncthreads();   // single barrier: drains K async prefetch + orders buffers
    }

    // epilogue: transpose O^T -> row-major via wave-private LDS region
#pragma unroll
    for (int ct = 0; ct < 8; ct++) {
#pragma unroll
        for (int pk = 0; pk < 4; pk++) {
            bf16x4 op;
            op[0] = (__bf16)acc[ct][pk * 4];     op[1] = (__bf16)acc[ct][pk * 4 + 1];
            op[2] = (__bf16)acc[ct][pk * 4 + 2]; op[3] = (__bf16)acc[ct][pk * 4 + 3];
            *(bf16x4*)&otr[wave][l32][ct * 32 + pk * 8 + h * 4] = op;
        }
    }
    if (lane < 32) {
        float2 v; v.x = mi; v.y = li;    // mi in log2 domain
        *(float2*)&ml[((size_t)ks * 16384 + rowg0 + l32) * 2] = v;
    }
    __syncthreads();
    __bf16* pobase = po + ((size_t)ks * 16384 + rowg0) * 256;
    const int rr = lane >> 1, half = lane & 1;
#pragma unroll
    for (int j = 0; j < 16; j++) {
        bf16x8 val = *(const bf16x8*)&otr[wave][rr][half * 128 + j * 8];
        *(bf16x8*)(pobase + (size_t)rr * 256 + half * 128 + j * 8) = val;
    }
}

// ---------------- Projection GEMM + fused 4-way merge + bias + residual ----------------
__global__ __launch_bounds__(128, 2) void proj_gemm(const __bf16* __restrict__ po,
                                                    const float* __restrict__ ml,
                                                    const __bf16* __restrict__ wpl,
                                                    const float* __restrict__ bp,
                                                    float* __restrict__ out) {
    __shared__ __bf16 atile[64][264];
    int tid = threadIdx.x;
    int wave = tid >> 6, lane = tid & 63;
    int quad = lane >> 4, l16 = lane & 15;
    int m0 = blockIdx.x * 64;
    int ntbase = blockIdx.y * 8 + wave * 4;

    // stage A-tile = merged attention output (4 key-split partials, exp2 domain)
#pragma unroll
    for (int i = 0; i < 16; i++) {
        int c = tid + 128 * i;
        int row = c >> 5, col8 = c & 31;
        int m = m0 + row;
        float mm[4], ll[4];
#pragma unroll
        for (int s = 0; s < 4; s++) {
            float2 v = *(const float2*)&ml[((size_t)s * 16384 + m) * 2];
            mm[s] = v.x; ll[s] = v.y;
        }
        float M = fmaxf(fmaxf(mm[0], mm[1]), fmaxf(mm[2], mm[3]));
        float den = 0.f, w[4];
#pragma unroll
        for (int s = 0; s < 4; s++) { w[s] = exp2f(mm[s] - M); den += ll[s] * w[s]; }
        float accv[8];
#pragma unroll
        for (int e = 0; e < 8; e++) accv[e] = 0.f;
#pragma unroll
        for (int s = 0; s < 4; s++) {
            bf16x8 pv = *(const bf16x8*)(po + ((size_t)s * 16384 + m) * 256 + col8 * 8);
#pragma unroll
            for (int e = 0; e < 8; e++) accv[e] += w[s] * (float)pv[e];
        }
        float rinv = 1.f / den;
        bf16x8 o;
#pragma unroll
        for (int e = 0; e < 8; e++) o[e] = (__bf16)(accv[e] * rinv);
        *(bf16x8*)&atile[row][col8 * 8] = o;
    }
    bf16x8 bfr[4][8];
#pragma unroll
    for (int ct = 0; ct < 4; ct++)
#pragma unroll
        for (int kf = 0; kf < 8; kf++)
            bfr[ct][kf] = *(const bf16x8*)(wpl + ((((size_t)(ntbase + ct) * 8 + kf) * 4 + quad) * 16 + l16) * 8);
    __syncthreads();

    f32x4 acc[4][4];
#pragma unroll
    for (int mt = 0; mt < 4; mt++)
#pragma unroll
        for (int ct = 0; ct < 4; ct++)
#pragma unroll
            for (int r = 0; r < 4; r++) acc[mt][ct][r] = 0.f;
#pragma unroll
    for (int kf = 0; kf < 8; kf++) {
        bf16x8 af[4];
#pragma unroll
        for (int mt = 0; mt < 4; mt++)
            af[mt] = *(const bf16x8*)&atile[mt * 16 + l16][kf * 32 + quad * 8];
#pragma unroll
        for (int mt = 0; mt < 4; mt++)
#pragma unroll
            for (int ct = 0; ct < 4; ct++)
                acc[mt][ct] = MFMA16(af[mt], bfr[ct][kf], acc[mt][ct]);
    }
#pragma unroll
    for (int mt = 0; mt < 4; mt++) {
#pragma unroll
        for (int ct = 0; ct < 4; ct++) {
            int c = (ntbase + ct) * 16 + l16;
            float bias_v = bp[c];
#pragma unroll
            for (int r = 0; r < 4; r++) {
                int m = m0 + mt * 16 + quad * 4 + r;
                size_t idx = (size_t)m * 256 + c;
                out[idx] = out[idx] + acc[mt][ct][r] + bias_v;
            }
        }
    }
}

extern "C" void kernel_launch(void* const* d_in, const int* in_sizes, int n_in,
                              void* d_out, int out_size, void* d_ws, size_t ws_size,
                              hipStream_t stream) {
    const float* x     = (const float*)d_in[0];
    const float* gamma = (const float*)d_in[1];
    const float* beta  = (const float*)d_in[2];
    const float* Wq    = (const float*)d_in[3];
    const float* bq    = (const float*)d_in[4];
    const float* Wk    = (const float*)d_in[5];
    const float* bk    = (const float*)d_in[6];
    const float* Wv    = (const float*)d_in[7];
    const float* bv    = (const float*)d_in[8];
    const float* Wp    = (const float*)d_in[9];
    const float* bp    = (const float*)d_in[10];
    float* out = (float*)d_out;

    char* ws = (char*)d_ws;
    __bf16* xn_bf   = (__bf16*)(ws);                    //  8,388,608 B
    __bf16* wt      = (__bf16*)(ws + 8388608);          //    524,288 B (fragment-linear)
    __bf16* qbuf    = (__bf16*)(ws + 8912896);          //  8,388,608 B
    __bf16* kbuf    = (__bf16*)(ws + 17301504);         //  8,388,608 B
    __bf16* vtbuf   = (__bf16*)(ws + 25690112);         //  8,388,608 B
    __bf16* po      = (__bf16*)(ws + 34078720);         // 33,554,432 B
    float*  ml      = (float*)(ws + 67633152);          //    524,288 B
    float*  pstats  = (float*)(ws + 68157440);          //      4,096 B
    float*  gstats  = (float*)(ws + 68161536);          //        256 B

    gn_stats1<<<512, 256, 0, stream>>>(x, pstats);
    gn_stats2<<<1, 64, 0, stream>>>(pstats, gstats);
    gn_norm<<<4096, 256, 0, stream>>>(x, gamma, beta, gstats, out, xn_bf);
    prep_w<<<1024, 256, 0, stream>>>(Wq, Wk, Wv, Wp, wt);
    qkv_gemm<<<dim3(256, 2, 3), 128, 0, stream>>>(xn_bf, wt, bq, bk, bv, qbuf, kbuf, vtbuf);
    flash_attn<<<dim3(32, 4, 4), 256, 0, stream>>>(qbuf, kbuf, vtbuf, po, ml);
    proj_gemm<<<dim3(256, 2), 128, 0, stream>>>(po, ml, wt + 3 * 65536, bp, out);
}